// Round 13
// baseline (151.324 us; speedup 1.0000x reference)
//
#include <hip/hip_runtime.h>
#include <math.h>

// SEM_40200893890649 R13: R12 + GRU-v4 (Wh@x hoisted into pass A; pass B stages only Uh).
//  K1 scorer (32x1024) | K2 scores (32x8 x512) | K3 merge+gathers (32x1024)
//  K5 GRU-v4 (32x16) | K6 GCN1-v2 (32x8) | K7 GCN2-v2 (32x8)

namespace {
constexpr int B_ = 32;
constexpr int N_ = 2000;
constexpr int D_ = 128;
constexpr int R_ = 640;

constexpr size_t OFF_SCORER = 0;
constexpr size_t OFF_INVN   = 4096;
constexpr size_t OFF_CANDV  = 4128;
constexpr size_t OFF_CANDI  = 20512;
constexpr size_t OFF_STATS  = 36896;
constexpr size_t OFF_TKI    = 37664;
constexpr size_t OFF_T0     = 39712;
constexpr size_t OFF_NE0T   = 41760;
constexpr size_t OFF_A0R    = 303904;
constexpr size_t OFF_DW     = 434976;
constexpr size_t OFF_H1     = 959264;

// =============== K1: scorer (R9 body, proven) ===============
__global__ __launch_bounds__(1024) void k1_scorer(
    const float* __restrict__ ht, const float* __restrict__ mw,
    const float* __restrict__ mb, float* __restrict__ scorer,
    float* __restrict__ invn, float* __restrict__ outScorer) {
  const int b = blockIdx.x, t = threadIdx.x;
  const int d = t & 127, slice = t >> 7;
  __shared__ float sh[R_];
  __shared__ float part[8][128];
  __shared__ float red[2];
  for (int j = t; j < R_; j += 1024) sh[j] = ht[b * R_ + j];
  __syncthreads();
  const float* wp = mw + (size_t)d * R_ + slice * 80;
  const float* hh = sh + slice * 80;
  float acc = 0.f;
  #pragma unroll
  for (int j = 0; j < 80; j += 4) {
    float4 wv = *reinterpret_cast<const float4*>(wp + j);
    acc += wv.x * hh[j] + wv.y * hh[j + 1] + wv.z * hh[j + 2] + wv.w * hh[j + 3];
  }
  part[slice][d] = acc;
  __syncthreads();
  if (t < 128) {
    float a = mb[t];
    #pragma unroll
    for (int s = 0; s < 8; ++s) a += part[s][t];
    const float sv = tanhf(a);
    scorer[b * D_ + t] = sv;
    outScorer[b * D_ + t] = sv;
    float ss = sv * sv;
    #pragma unroll
    for (int o = 32; o > 0; o >>= 1) ss += __shfl_down(ss, o);
    if ((t & 63) == 0) red[t >> 6] = ss;
  }
  __syncthreads();
  if (t == 0) invn[b] = 1.0f / sqrtf(red[0] + red[1]);
}

// =============== K2: chunk scores (R9/R11 body, proven) ===============
__global__ __launch_bounds__(512) void k2_scores(
    const float* __restrict__ node, const float* __restrict__ scorer,
    const float* __restrict__ invn, float* __restrict__ cand_v,
    int* __restrict__ cand_i, float* __restrict__ stats) {
  const int b = blockIdx.x, c = blockIdx.y, t = threadIdx.x;
  const int cand = t & 255, s = t >> 8;
  const int lane = t & 63, w = t >> 6;
  __shared__ float sc[D_];
  __shared__ float pd[256][2];
  __shared__ float cv[256];
  __shared__ int ci[256];
  __shared__ int pr[256][2];
  __shared__ float r1[8], r2[8];
  if (t < D_) sc[t] = scorer[b * D_ + t];
  __syncthreads();
  const float inv = invn[b];
  const int n = c * 250 + cand;
  const bool valid = cand < 250;
  {
    float acc = 0.f;
    if (valid) {
      const float* row = node + ((size_t)b * N_ + n) * D_ + s * 64;
      const float* scp = sc + s * 64;
      #pragma unroll
      for (int j = 0; j < 64; j += 4) {
        float4 a = *reinterpret_cast<const float4*>(row + j);
        acc += a.x * scp[j] + a.y * scp[j + 1] + a.z * scp[j + 2] + a.w * scp[j + 3];
      }
    }
    pd[cand][s] = acc;
  }
  __syncthreads();
  float v = -INFINITY;
  if (s == 0 && valid) v = (pd[cand][0] + pd[cand][1]) * inv;
  float m = v;
  #pragma unroll
  for (int o = 32; o > 0; o >>= 1) m = fmaxf(m, __shfl_xor(m, o));
  if (lane == 0) r1[w] = m;
  __syncthreads();
  float Mc = r1[0];
  #pragma unroll
  for (int q = 1; q < 8; ++q) Mc = fmaxf(Mc, r1[q]);
  __syncthreads();
  float se = 0.f, sx = 0.f;
  if (s == 0 && valid) {
    const float x = v - Mc;
    const float e = expf(x);
    se = e;
    sx = x * e;
  }
  #pragma unroll
  for (int o = 32; o > 0; o >>= 1) {
    se += __shfl_xor(se, o);
    sx += __shfl_xor(sx, o);
  }
  if (lane == 0) { r1[w] = se; r2[w] = sx; }
  if (s == 0) {
    cv[cand] = v;
    ci[cand] = valid ? n : 0x7fffffff;
  }
  __syncthreads();
  if (t == 0) {
    float Se = 0.f, Sx = 0.f;
    #pragma unroll
    for (int q = 0; q < 8; ++q) { Se += r1[q]; Sx += r2[q]; }
    float* st = stats + ((size_t)b * 8 + c) * 3;
    st[0] = Mc;
    st[1] = Se;
    st[2] = Sx;
  }
  {
    const float mv = cv[cand];
    const int mi = ci[cand];
    int rank = 0;
    const int j0 = s * 128;
    for (int j = j0; j < j0 + 128; ++j) {
      const float jv = cv[j];
      const int ji = ci[j];
      rank += (jv > mv || (jv == mv && ji < mi)) ? 1 : 0;
    }
    pr[cand][s] = rank;
  }
  __syncthreads();
  if (s == 0 && valid) {
    const int rk = pr[cand][0] + pr[cand][1];
    if (rk < 64) {
      cand_v[((size_t)b * 8 + c) * 64 + rk] = cv[cand];
      cand_i[((size_t)b * 8 + c) * 64 + rk] = ci[cand];
    }
  }
}

// =============== K3: merge + policy + ne0T + A-gather (R11 body, proven) ===============
__global__ __launch_bounds__(1024) void k3_merge(
    const float* __restrict__ cand_v, const int* __restrict__ cand_i,
    const float* __restrict__ stats, const float* __restrict__ node,
    const float* __restrict__ Ahat, int* __restrict__ tki,
    float* __restrict__ t0v, float* __restrict__ outPolicy,
    float* __restrict__ outEntropy, float* __restrict__ ne0T,
    float* __restrict__ A0r) {
  const int b = blockIdx.x, t = threadIdx.x;
  const int cand = t & 511, s = t >> 9;
  __shared__ float cv[512];
  __shared__ int ci[512];
  __shared__ int pr[512][2];
  __shared__ float sv[64];
  __shared__ int si[64];
  __shared__ float lne[64][132];
  if (t < 512) {
    cv[t] = cand_v[(size_t)b * 512 + t];
    ci[t] = cand_i[(size_t)b * 512 + t];
  }
  __syncthreads();
  {
    const float mv = cv[cand];
    const int mi = ci[cand];
    int rank = 0;
    const int j0 = s * 256;
    for (int j = j0; j < j0 + 256; ++j) {
      const float jv = cv[j];
      const int ji = ci[j];
      rank += (jv > mv || (jv == mv && ji < mi)) ? 1 : 0;
    }
    pr[cand][s] = rank;
  }
  __syncthreads();
  if (s == 0) {
    const int rk = pr[cand][0] + pr[cand][1];
    if (rk < 64) { sv[rk] = cv[cand]; si[rk] = ci[cand]; }
  }
  __syncthreads();
  {
    const float* Ab = Ahat + (size_t)b * N_ * N_;
    float* dst = A0r + (size_t)b * 4096;
    const int e0 = t * 4;
    #pragma unroll
    for (int j = 0; j < 4; ++j) {
      const int e = e0 + j;
      dst[e] = Ab[(size_t)si[e >> 6] * N_ + si[e & 63]];
    }
  }
  if (t < 64) {
    tki[b * 64 + t] = si[t];
    const float v = sv[t];
    t0v[b * 64 + t] = tanhf(v);
    float sum = v;
    #pragma unroll
    for (int o = 32; o > 0; o >>= 1) sum += __shfl_xor(sum, o);
    if (t == 0) {
      float M = -INFINITY;
      for (int c = 0; c < 8; ++c) M = fmaxf(M, stats[((size_t)b * 8 + c) * 3]);
      float se = 0.f, sx = 0.f;
      for (int c = 0; c < 8; ++c) {
        const float* st = stats + ((size_t)b * 8 + c) * 3;
        const float f = expf(st[0] - M);
        se += f * st[1];
        sx += f * (st[2] + (st[0] - M) * st[1]);
      }
      const float logS = logf(se);
      outPolicy[b] = sum * (1.0f / 64.0f) - M - logS;
      outEntropy[b] = logS - sx / se;
    }
  }
  __syncthreads();
  {
    const int k = t >> 4, q = t & 15;
    const float* src = node + ((size_t)b * N_ + si[k]) * D_ + q * 8;
    *reinterpret_cast<float4*>(&lne[k][q * 8]) =
        *reinterpret_cast<const float4*>(src);
    *reinterpret_cast<float4*>(&lne[k][q * 8 + 4]) =
        *reinterpret_cast<const float4*>(src + 4);
  }
  __syncthreads();
  {
    const int f = t >> 3, kh = (t & 7) * 8;
    float* dst = ne0T + ((size_t)b * D_ + f) * 64 + kh;
    float4 a, bq;
    a.x = lne[kh][f];     a.y = lne[kh + 1][f];
    a.z = lne[kh + 2][f]; a.w = lne[kh + 3][f];
    bq.x = lne[kh + 4][f]; bq.y = lne[kh + 5][f];
    bq.z = lne[kh + 6][f]; bq.w = lne[kh + 7][f];
    *reinterpret_cast<float4*>(dst) = a;
    *reinterpret_cast<float4*>(dst + 4) = bq;
  }
}

// =============== K5: GRU-v4 — Wh@x hoisted to pass A; pass B stages only Uh ===============
// grid (32,16), block 256 = 4 waves; wave owns rows w*32..w*32+31 of the 8-col chunk.
__global__ __launch_bounds__(256) void k5_gru(
    const float* __restrict__ Wu, const float* __restrict__ Uu, const float* __restrict__ bu,
    const float* __restrict__ Wr, const float* __restrict__ Ur, const float* __restrict__ br,
    const float* __restrict__ Wh, const float* __restrict__ Uh, const float* __restrict__ bh,
    const float* __restrict__ ne0T, const float* __restrict__ t0v,
    const float* __restrict__ P, float* __restrict__ Dw) {
  const int b = blockIdx.x, c = blockIdx.y;  // c 0..15
  const int t = threadIdx.x;
  const int w = t >> 6, l = t & 63;
  const int tx = l & 7, ry = l >> 3;
  __shared__ float WA[4][16][40], UA[4][16][40];  // pass A: Wu,Uu | pass B: Uh in WA
  __shared__ float WB[4][16][40], UB[4][16][40];  // pass A: Wr,Ur
  __shared__ float WH[4][16][40];                 // pass A: Wh
  __shared__ float Xl[4][16][8], Yl[4][16][8];
  __shared__ float gr[128][9];                    // r-gate (cross-wave)
  const int row0 = w * 32;
  const int col = c * 8 + tx;
  const float t0c = t0v[b * 64 + (c & 7) * 8 + tx];
  const float* neT = ne0T + (size_t)b * D_ * 64;
  const float* Pb = P + (size_t)b * D_ * D_;
  const int sr = l >> 1, h = l & 1;
  const int e0 = l * 2;
  const int xff = e0 >> 3, xkk = e0 & 7;

  // -------- pass A: u-gate, r-gate, and Wh@x (no block barriers) --------
  float aU[4] = {}, aR[4] = {}, aHx[4] = {};
  for (int f0 = 0; f0 < D_; f0 += 16) {
    {
      const size_t rb = (size_t)(row0 + sr) * D_ + f0 + h * 8;
      const float4 wu0 = *reinterpret_cast<const float4*>(Wu + rb);
      const float4 wu1 = *reinterpret_cast<const float4*>(Wu + rb + 4);
      const float4 uu0 = *reinterpret_cast<const float4*>(Uu + rb);
      const float4 uu1 = *reinterpret_cast<const float4*>(Uu + rb + 4);
      const float4 wr0 = *reinterpret_cast<const float4*>(Wr + rb);
      const float4 wr1 = *reinterpret_cast<const float4*>(Wr + rb + 4);
      const float4 ur0 = *reinterpret_cast<const float4*>(Ur + rb);
      const float4 ur1 = *reinterpret_cast<const float4*>(Ur + rb + 4);
      const float4 wh0 = *reinterpret_cast<const float4*>(Wh + rb);
      const float4 wh1 = *reinterpret_cast<const float4*>(Wh + rb + 4);
      const float wuv[8] = {wu0.x, wu0.y, wu0.z, wu0.w, wu1.x, wu1.y, wu1.z, wu1.w};
      const float uuv[8] = {uu0.x, uu0.y, uu0.z, uu0.w, uu1.x, uu1.y, uu1.z, uu1.w};
      const float wrv[8] = {wr0.x, wr0.y, wr0.z, wr0.w, wr1.x, wr1.y, wr1.z, wr1.w};
      const float urv[8] = {ur0.x, ur0.y, ur0.z, ur0.w, ur1.x, ur1.y, ur1.z, ur1.w};
      const float whv[8] = {wh0.x, wh0.y, wh0.z, wh0.w, wh1.x, wh1.y, wh1.z, wh1.w};
      #pragma unroll
      for (int j = 0; j < 8; ++j) {
        WA[w][h * 8 + j][sr] = wuv[j];
        UA[w][h * 8 + j][sr] = uuv[j];
        WB[w][h * 8 + j][sr] = wrv[j];
        UB[w][h * 8 + j][sr] = urv[j];
        WH[w][h * 8 + j][sr] = whv[j];
      }
      #pragma unroll
      for (int e = 0; e < 2; ++e) {
        const int ff = xff, kk = xkk + e;
        Xl[w][ff][kk] = neT[(f0 + ff) * 64 + (c & 7) * 8 + kk];
        Yl[w][ff][kk] = Pb[(size_t)(f0 + ff) * D_ + c * 8 + kk];
      }
    }
    __builtin_amdgcn_wave_barrier();
    #pragma unroll
    for (int ff = 0; ff < 16; ++ff) {
      const float xv = Xl[w][ff][tx] * t0c;
      const float yv = Yl[w][ff][tx];
      const float4 wa = *reinterpret_cast<const float4*>(&WA[w][ff][ry * 4]);
      const float4 ua = *reinterpret_cast<const float4*>(&UA[w][ff][ry * 4]);
      const float4 wb = *reinterpret_cast<const float4*>(&WB[w][ff][ry * 4]);
      const float4 ub = *reinterpret_cast<const float4*>(&UB[w][ff][ry * 4]);
      const float4 wh = *reinterpret_cast<const float4*>(&WH[w][ff][ry * 4]);
      aU[0] += wa.x * xv + ua.x * yv;
      aU[1] += wa.y * xv + ua.y * yv;
      aU[2] += wa.z * xv + ua.z * yv;
      aU[3] += wa.w * xv + ua.w * yv;
      aR[0] += wb.x * xv + ub.x * yv;
      aR[1] += wb.y * xv + ub.y * yv;
      aR[2] += wb.z * xv + ub.z * yv;
      aR[3] += wb.w * xv + ub.w * yv;
      aHx[0] += wh.x * xv;
      aHx[1] += wh.y * xv;
      aHx[2] += wh.z * xv;
      aHx[3] += wh.w * xv;
    }
    __builtin_amdgcn_wave_barrier();
  }
  float uval[4];
  #pragma unroll
  for (int r = 0; r < 4; ++r) {
    const int i = row0 + ry * 4 + r;
    uval[r] = 1.f / (1.f + expf(-(aU[r] + bu[i * D_ + col])));
    gr[i][tx] = 1.f / (1.f + expf(-(aR[r] + br[i * D_ + col])));
  }
  __syncthreads();  // the ONE block barrier

  // -------- pass B: aH = aHx + Uh@(r·P) --------
  float aH[4] = {aHx[0], aHx[1], aHx[2], aHx[3]};
  for (int f0 = 0; f0 < D_; f0 += 16) {
    {
      const size_t rb = (size_t)(row0 + sr) * D_ + f0 + h * 8;
      const float4 uh0 = *reinterpret_cast<const float4*>(Uh + rb);
      const float4 uh1 = *reinterpret_cast<const float4*>(Uh + rb + 4);
      const float uhv[8] = {uh0.x, uh0.y, uh0.z, uh0.w, uh1.x, uh1.y, uh1.z, uh1.w};
      #pragma unroll
      for (int j = 0; j < 8; ++j) WA[w][h * 8 + j][sr] = uhv[j];
      #pragma unroll
      for (int e = 0; e < 2; ++e) {
        const int ff = xff, kk = xkk + e;
        Yl[w][ff][kk] = gr[f0 + ff][kk] * Pb[(size_t)(f0 + ff) * D_ + c * 8 + kk];
      }
    }
    __builtin_amdgcn_wave_barrier();
    #pragma unroll
    for (int ff = 0; ff < 16; ++ff) {
      const float yv = Yl[w][ff][tx];
      const float4 ua = *reinterpret_cast<const float4*>(&WA[w][ff][ry * 4]);
      aH[0] += ua.x * yv;
      aH[1] += ua.y * yv;
      aH[2] += ua.z * yv;
      aH[3] += ua.w * yv;
    }
    __builtin_amdgcn_wave_barrier();
  }
  #pragma unroll
  for (int r = 0; r < 4; ++r) {
    const int i = row0 + ry * 4 + r;
    const float hh = tanhf(aH[r] + bh[i * D_ + col]);
    const float pp = Pb[(size_t)i * D_ + col];
    Dw[((size_t)b * D_ + i) * D_ + col] = (1.f - uval[r]) * pp + uval[r] * hh;
  }
}

// =============== K6: GCN1-v2 — 3 barriers (R12 body, proven) ===============
__global__ __launch_bounds__(256) void k6_gcn1(
    const float* __restrict__ ne0T, const float* __restrict__ Dw,
    const float* __restrict__ A0r, float* __restrict__ h1ws) {
  const int b = blockIdx.x, c = blockIdx.y;
  const int t = threadIdx.x;
  const int w = t >> 6, l = t & 63;
  const int tx = t & 15, ty = t >> 4;
  const int cg = l & 3, rg = l >> 2;
  const int row = w * 16 + rg;
  __shared__ float As[64][68];
  __shared__ float di[64];
  __shared__ float Ts[64][24];
  __shared__ float At[4][16][24], Bt[4][16][24];
  const float* Ab = A0r + (size_t)b * 4096;
  const float* neT = ne0T + (size_t)b * D_ * 64;
  const float* Db = Dw + (size_t)b * D_ * D_;
  #pragma unroll
  for (int ph = 0; ph < 4; ++ph) {
    const int i = ph * 16 + ty;
    *reinterpret_cast<float4*>(&As[i][tx * 4]) =
        *reinterpret_cast<const float4*>(Ab + i * 64 + tx * 4);
  }
  __syncthreads();
  if (t < 64) {
    float s = 0.f;
    #pragma unroll
    for (int i = 0; i < 64; ++i) s += As[i][t];
    di[t] = 1.0f / sqrtf(2.0f * s);
  }
  __syncthreads();
  #pragma unroll
  for (int ph = 0; ph < 4; ++ph) {
    const int i = ph * 16 + ty;
    const float sI = 2.0f * di[i];
    float4 v = *reinterpret_cast<float4*>(&As[i][tx * 4]);
    v.x *= sI * di[tx * 4];
    v.y *= sI * di[tx * 4 + 1];
    v.z *= sI * di[tx * 4 + 2];
    v.w *= sI * di[tx * 4 + 3];
    *reinterpret_cast<float4*>(&As[i][tx * 4]) = v;
  }
  const int sff = l >> 2, sq = (l & 3) * 4;
  float acc[4] = {};
  for (int f0 = 0; f0 < D_; f0 += 16) {
    {
      const float4 av = *reinterpret_cast<const float4*>(neT + (f0 + sff) * 64 + w * 16 + sq);
      *reinterpret_cast<float4*>(&At[w][sff][sq]) = av;
      const float4 bv = *reinterpret_cast<const float4*>(Db + (size_t)(f0 + sff) * D_ + c * 16 + sq);
      *reinterpret_cast<float4*>(&Bt[w][sff][sq]) = bv;
    }
    __builtin_amdgcn_wave_barrier();
    #pragma unroll
    for (int ff = 0; ff < 16; ++ff) {
      const float a = At[w][ff][rg];
      const float4 b4 = *reinterpret_cast<const float4*>(&Bt[w][ff][cg * 4]);
      acc[0] += a * b4.x;
      acc[1] += a * b4.y;
      acc[2] += a * b4.z;
      acc[3] += a * b4.w;
    }
    __builtin_amdgcn_wave_barrier();
  }
  {
    float4 o = {acc[0], acc[1], acc[2], acc[3]};
    *reinterpret_cast<float4*>(&Ts[row][cg * 4]) = o;
  }
  __syncthreads();
  float a2[4] = {};
  for (int ff = 0; ff < 64; ++ff) {
    const float a = As[row][ff];
    const float4 b4 = *reinterpret_cast<const float4*>(&Ts[ff][cg * 4]);
    a2[0] += a * b4.x;
    a2[1] += a * b4.y;
    a2[2] += a * b4.z;
    a2[3] += a * b4.w;
  }
  {
    float4 o = {fmaxf(a2[0], 0.f), fmaxf(a2[1], 0.f),
                fmaxf(a2[2], 0.f), fmaxf(a2[3], 0.f)};
    *reinterpret_cast<float4*>(h1ws + ((size_t)b * 64 + row) * D_ + c * 16 + cg * 4) = o;
  }
}

// =============== K7: GCN2-v2 — 3 barriers (R12 body, proven) ===============
__global__ __launch_bounds__(256) void k7_gcn2(
    const float* __restrict__ h1ws, const float* __restrict__ sw,
    const float* __restrict__ A0r, float* __restrict__ out) {
  const int b = blockIdx.x, c = blockIdx.y;
  const int t = threadIdx.x;
  const int w = t >> 6, l = t & 63;
  const int tx = t & 15, ty = t >> 4;
  const int cg = l & 3, rg = l >> 2;
  const int row = w * 16 + rg;
  __shared__ float As[64][68];
  __shared__ float di[64];
  __shared__ float Ts[64][24];
  __shared__ float At[4][16][24], Bt[4][16][24];
  const float* Ab = A0r + (size_t)b * 4096;
  const float* h1b = h1ws + (size_t)b * 64 * D_;
  #pragma unroll
  for (int ph = 0; ph < 4; ++ph) {
    const int i = ph * 16 + ty;
    *reinterpret_cast<float4*>(&As[i][tx * 4]) =
        *reinterpret_cast<const float4*>(Ab + i * 64 + tx * 4);
  }
  __syncthreads();
  if (t < 64) {
    float s = 0.f;
    #pragma unroll
    for (int i = 0; i < 64; ++i) s += As[i][t];
    di[t] = 1.0f / sqrtf(2.0f * s);
  }
  __syncthreads();
  #pragma unroll
  for (int ph = 0; ph < 4; ++ph) {
    const int i = ph * 16 + ty;
    const float sI = 2.0f * di[i];
    float4 v = *reinterpret_cast<float4*>(&As[i][tx * 4]);
    v.x *= sI * di[tx * 4];
    v.y *= sI * di[tx * 4 + 1];
    v.z *= sI * di[tx * 4 + 2];
    v.w *= sI * di[tx * 4 + 3];
    *reinterpret_cast<float4*>(&As[i][tx * 4]) = v;
  }
  const int sr16 = l & 15, sh4 = l >> 4;
  const int sff = l >> 2, sq = (l & 3) * 4;
  float acc[4] = {};
  for (int f0 = 0; f0 < D_; f0 += 16) {
    {
      const float4 hv = *reinterpret_cast<const float4*>(
          h1b + (size_t)(w * 16 + sr16) * D_ + f0 + sh4 * 4);
      At[w][sh4 * 4 + 0][sr16] = hv.x;
      At[w][sh4 * 4 + 1][sr16] = hv.y;
      At[w][sh4 * 4 + 2][sr16] = hv.z;
      At[w][sh4 * 4 + 3][sr16] = hv.w;
      const float4 bv = *reinterpret_cast<const float4*>(sw + (size_t)(f0 + sff) * D_ + c * 16 + sq);
      *reinterpret_cast<float4*>(&Bt[w][sff][sq]) = bv;
    }
    __builtin_amdgcn_wave_barrier();
    #pragma unroll
    for (int ff = 0; ff < 16; ++ff) {
      const float a = At[w][ff][rg];
      const float4 b4 = *reinterpret_cast<const float4*>(&Bt[w][ff][cg * 4]);
      acc[0] += a * b4.x;
      acc[1] += a * b4.y;
      acc[2] += a * b4.z;
      acc[3] += a * b4.w;
    }
    __builtin_amdgcn_wave_barrier();
  }
  {
    float4 o = {acc[0], acc[1], acc[2], acc[3]};
    *reinterpret_cast<float4*>(&Ts[row][cg * 4]) = o;
  }
  __syncthreads();
  float a2[4] = {};
  for (int ff = 0; ff < 64; ++ff) {
    const float a = As[row][ff];
    const float4 b4 = *reinterpret_cast<const float4*>(&Ts[ff][cg * 4]);
    a2[0] += a * b4.x;
    a2[1] += a * b4.y;
    a2[2] += a * b4.z;
    a2[3] += a * b4.w;
  }
  {
    const int k = c * 16 + cg * 4;
    const float4 h1v = *reinterpret_cast<const float4*>(h1b + (size_t)row * D_ + k);
    float4 o;
    o.x = 0.5f * (h1v.x + fmaxf(a2[0], 0.f));
    o.y = 0.5f * (h1v.y + fmaxf(a2[1], 0.f));
    o.z = 0.5f * (h1v.z + fmaxf(a2[2], 0.f));
    o.w = 0.5f * (h1v.w + fmaxf(a2[3], 0.f));
    *reinterpret_cast<float4*>(out + ((size_t)b * D_ + row) * D_ + k) = o;
    *reinterpret_cast<float4*>(out + ((size_t)b * D_ + row + 64) * D_ + k) = o;
  }
}

}  // namespace

extern "C" void kernel_launch(void* const* d_in, const int* in_sizes, int n_in,
                              void* d_out, int out_size, void* d_ws, size_t ws_size,
                              hipStream_t stream) {
  (void)in_sizes; (void)n_in; (void)out_size; (void)ws_size;
  const float* Ahat = (const float*)d_in[0];
  const float* node = (const float*)d_in[1];
  const float* ht   = (const float*)d_in[2];
  const float* prevD= (const float*)d_in[3];
  const float* mw   = (const float*)d_in[4];
  const float* mb   = (const float*)d_in[5];
  const float* Wu   = (const float*)d_in[6];
  const float* Uu   = (const float*)d_in[7];
  const float* bu   = (const float*)d_in[8];
  const float* Wr   = (const float*)d_in[9];
  const float* Ur   = (const float*)d_in[10];
  const float* br   = (const float*)d_in[11];
  const float* Wh   = (const float*)d_in[12];
  const float* Uh   = (const float*)d_in[13];
  const float* bh   = (const float*)d_in[14];
  const float* sw   = (const float*)d_in[15];

  float* out = (float*)d_out;
  float* outPolicy  = out + (size_t)B_ * D_ * D_;
  float* outScorer  = outPolicy + B_;
  float* outEntropy = outScorer + (size_t)B_ * D_;

  float* ws = (float*)d_ws;
  float* scorer = ws + OFF_SCORER;
  float* invn   = ws + OFF_INVN;
  float* cand_v = ws + OFF_CANDV;
  int*   cand_i = (int*)(ws + OFF_CANDI);
  float* stats  = ws + OFF_STATS;
  int*   tki    = (int*)(ws + OFF_TKI);
  float* t0v    = ws + OFF_T0;
  float* ne0T   = ws + OFF_NE0T;
  float* A0r    = ws + OFF_A0R;
  float* Dw     = ws + OFF_DW;
  float* h1ws   = ws + OFF_H1;

  k1_scorer<<<B_, 1024, 0, stream>>>(ht, mw, mb, scorer, invn, outScorer);
  k2_scores<<<dim3(B_, 8), 512, 0, stream>>>(node, scorer, invn, cand_v, cand_i, stats);
  k3_merge<<<B_, 1024, 0, stream>>>(cand_v, cand_i, stats, node, Ahat, tki, t0v,
                                    outPolicy, outEntropy, ne0T, A0r);
  k5_gru<<<dim3(B_, 16), 256, 0, stream>>>(Wu, Uu, bu, Wr, Ur, br, Wh, Uh, bh,
                                           ne0T, t0v, prevD, Dw);
  k6_gcn1<<<dim3(B_, 8), 256, 0, stream>>>(ne0T, Dw, A0r, h1ws);
  k7_gcn2<<<dim3(B_, 8), 256, 0, stream>>>(h1ws, sw, A0r, out);
}

// Round 14
// 117.709 us; speedup vs baseline: 1.2856x; 1.2856x over previous
//
#include <hip/hip_runtime.h>
#include <math.h>

// SEM_40200893890649 R14 = R12 verbatim (proven 117.9 us; R13's GRU-v4 regressed).
//  K1 scorer (32x1024) | K2 scores (32x8 x512) | K3 merge+gathers (32x1024)
//  K5 GRU-v3: 1 barrier (32x16) | K6 GCN1-v2: 3 barriers (32x8) | K7 GCN2-v2: 3 barriers (32x8)

namespace {
constexpr int B_ = 32;
constexpr int N_ = 2000;
constexpr int D_ = 128;
constexpr int R_ = 640;

constexpr size_t OFF_SCORER = 0;
constexpr size_t OFF_INVN   = 4096;
constexpr size_t OFF_CANDV  = 4128;
constexpr size_t OFF_CANDI  = 20512;
constexpr size_t OFF_STATS  = 36896;
constexpr size_t OFF_TKI    = 37664;
constexpr size_t OFF_T0     = 39712;
constexpr size_t OFF_NE0T   = 41760;
constexpr size_t OFF_A0R    = 303904;
constexpr size_t OFF_DW     = 434976;
constexpr size_t OFF_H1     = 959264;

// =============== K1: scorer (R9 body, proven) ===============
__global__ __launch_bounds__(1024) void k1_scorer(
    const float* __restrict__ ht, const float* __restrict__ mw,
    const float* __restrict__ mb, float* __restrict__ scorer,
    float* __restrict__ invn, float* __restrict__ outScorer) {
  const int b = blockIdx.x, t = threadIdx.x;
  const int d = t & 127, slice = t >> 7;
  __shared__ float sh[R_];
  __shared__ float part[8][128];
  __shared__ float red[2];
  for (int j = t; j < R_; j += 1024) sh[j] = ht[b * R_ + j];
  __syncthreads();
  const float* wp = mw + (size_t)d * R_ + slice * 80;
  const float* hh = sh + slice * 80;
  float acc = 0.f;
  #pragma unroll
  for (int j = 0; j < 80; j += 4) {
    float4 wv = *reinterpret_cast<const float4*>(wp + j);
    acc += wv.x * hh[j] + wv.y * hh[j + 1] + wv.z * hh[j + 2] + wv.w * hh[j + 3];
  }
  part[slice][d] = acc;
  __syncthreads();
  if (t < 128) {
    float a = mb[t];
    #pragma unroll
    for (int s = 0; s < 8; ++s) a += part[s][t];
    const float sv = tanhf(a);
    scorer[b * D_ + t] = sv;
    outScorer[b * D_ + t] = sv;
    float ss = sv * sv;
    #pragma unroll
    for (int o = 32; o > 0; o >>= 1) ss += __shfl_down(ss, o);
    if ((t & 63) == 0) red[t >> 6] = ss;
  }
  __syncthreads();
  if (t == 0) invn[b] = 1.0f / sqrtf(red[0] + red[1]);
}

// =============== K2: chunk scores (R9/R11 body, proven) ===============
__global__ __launch_bounds__(512) void k2_scores(
    const float* __restrict__ node, const float* __restrict__ scorer,
    const float* __restrict__ invn, float* __restrict__ cand_v,
    int* __restrict__ cand_i, float* __restrict__ stats) {
  const int b = blockIdx.x, c = blockIdx.y, t = threadIdx.x;
  const int cand = t & 255, s = t >> 8;
  const int lane = t & 63, w = t >> 6;
  __shared__ float sc[D_];
  __shared__ float pd[256][2];
  __shared__ float cv[256];
  __shared__ int ci[256];
  __shared__ int pr[256][2];
  __shared__ float r1[8], r2[8];
  if (t < D_) sc[t] = scorer[b * D_ + t];
  __syncthreads();
  const float inv = invn[b];
  const int n = c * 250 + cand;
  const bool valid = cand < 250;
  {
    float acc = 0.f;
    if (valid) {
      const float* row = node + ((size_t)b * N_ + n) * D_ + s * 64;
      const float* scp = sc + s * 64;
      #pragma unroll
      for (int j = 0; j < 64; j += 4) {
        float4 a = *reinterpret_cast<const float4*>(row + j);
        acc += a.x * scp[j] + a.y * scp[j + 1] + a.z * scp[j + 2] + a.w * scp[j + 3];
      }
    }
    pd[cand][s] = acc;
  }
  __syncthreads();
  float v = -INFINITY;
  if (s == 0 && valid) v = (pd[cand][0] + pd[cand][1]) * inv;
  float m = v;
  #pragma unroll
  for (int o = 32; o > 0; o >>= 1) m = fmaxf(m, __shfl_xor(m, o));
  if (lane == 0) r1[w] = m;
  __syncthreads();
  float Mc = r1[0];
  #pragma unroll
  for (int q = 1; q < 8; ++q) Mc = fmaxf(Mc, r1[q]);
  __syncthreads();
  float se = 0.f, sx = 0.f;
  if (s == 0 && valid) {
    const float x = v - Mc;
    const float e = expf(x);
    se = e;
    sx = x * e;
  }
  #pragma unroll
  for (int o = 32; o > 0; o >>= 1) {
    se += __shfl_xor(se, o);
    sx += __shfl_xor(sx, o);
  }
  if (lane == 0) { r1[w] = se; r2[w] = sx; }
  if (s == 0) {
    cv[cand] = v;
    ci[cand] = valid ? n : 0x7fffffff;
  }
  __syncthreads();
  if (t == 0) {
    float Se = 0.f, Sx = 0.f;
    #pragma unroll
    for (int q = 0; q < 8; ++q) { Se += r1[q]; Sx += r2[q]; }
    float* st = stats + ((size_t)b * 8 + c) * 3;
    st[0] = Mc;
    st[1] = Se;
    st[2] = Sx;
  }
  {
    const float mv = cv[cand];
    const int mi = ci[cand];
    int rank = 0;
    const int j0 = s * 128;
    for (int j = j0; j < j0 + 128; ++j) {
      const float jv = cv[j];
      const int ji = ci[j];
      rank += (jv > mv || (jv == mv && ji < mi)) ? 1 : 0;
    }
    pr[cand][s] = rank;
  }
  __syncthreads();
  if (s == 0 && valid) {
    const int rk = pr[cand][0] + pr[cand][1];
    if (rk < 64) {
      cand_v[((size_t)b * 8 + c) * 64 + rk] = cv[cand];
      cand_i[((size_t)b * 8 + c) * 64 + rk] = ci[cand];
    }
  }
}

// =============== K3: merge + policy + ne0T + A-gather (R11 body, proven) ===============
__global__ __launch_bounds__(1024) void k3_merge(
    const float* __restrict__ cand_v, const int* __restrict__ cand_i,
    const float* __restrict__ stats, const float* __restrict__ node,
    const float* __restrict__ Ahat, int* __restrict__ tki,
    float* __restrict__ t0v, float* __restrict__ outPolicy,
    float* __restrict__ outEntropy, float* __restrict__ ne0T,
    float* __restrict__ A0r) {
  const int b = blockIdx.x, t = threadIdx.x;
  const int cand = t & 511, s = t >> 9;
  __shared__ float cv[512];
  __shared__ int ci[512];
  __shared__ int pr[512][2];
  __shared__ float sv[64];
  __shared__ int si[64];
  __shared__ float lne[64][132];
  if (t < 512) {
    cv[t] = cand_v[(size_t)b * 512 + t];
    ci[t] = cand_i[(size_t)b * 512 + t];
  }
  __syncthreads();
  {
    const float mv = cv[cand];
    const int mi = ci[cand];
    int rank = 0;
    const int j0 = s * 256;
    for (int j = j0; j < j0 + 256; ++j) {
      const float jv = cv[j];
      const int ji = ci[j];
      rank += (jv > mv || (jv == mv && ji < mi)) ? 1 : 0;
    }
    pr[cand][s] = rank;
  }
  __syncthreads();
  if (s == 0) {
    const int rk = pr[cand][0] + pr[cand][1];
    if (rk < 64) { sv[rk] = cv[cand]; si[rk] = ci[cand]; }
  }
  __syncthreads();
  {
    const float* Ab = Ahat + (size_t)b * N_ * N_;
    float* dst = A0r + (size_t)b * 4096;
    const int e0 = t * 4;
    #pragma unroll
    for (int j = 0; j < 4; ++j) {
      const int e = e0 + j;
      dst[e] = Ab[(size_t)si[e >> 6] * N_ + si[e & 63]];
    }
  }
  if (t < 64) {
    tki[b * 64 + t] = si[t];
    const float v = sv[t];
    t0v[b * 64 + t] = tanhf(v);
    float sum = v;
    #pragma unroll
    for (int o = 32; o > 0; o >>= 1) sum += __shfl_xor(sum, o);
    if (t == 0) {
      float M = -INFINITY;
      for (int c = 0; c < 8; ++c) M = fmaxf(M, stats[((size_t)b * 8 + c) * 3]);
      float se = 0.f, sx = 0.f;
      for (int c = 0; c < 8; ++c) {
        const float* st = stats + ((size_t)b * 8 + c) * 3;
        const float f = expf(st[0] - M);
        se += f * st[1];
        sx += f * (st[2] + (st[0] - M) * st[1]);
      }
      const float logS = logf(se);
      outPolicy[b] = sum * (1.0f / 64.0f) - M - logS;
      outEntropy[b] = logS - sx / se;
    }
  }
  __syncthreads();
  {
    const int k = t >> 4, q = t & 15;
    const float* src = node + ((size_t)b * N_ + si[k]) * D_ + q * 8;
    *reinterpret_cast<float4*>(&lne[k][q * 8]) =
        *reinterpret_cast<const float4*>(src);
    *reinterpret_cast<float4*>(&lne[k][q * 8 + 4]) =
        *reinterpret_cast<const float4*>(src + 4);
  }
  __syncthreads();
  {
    const int f = t >> 3, kh = (t & 7) * 8;
    float* dst = ne0T + ((size_t)b * D_ + f) * 64 + kh;
    float4 a, bq;
    a.x = lne[kh][f];     a.y = lne[kh + 1][f];
    a.z = lne[kh + 2][f]; a.w = lne[kh + 3][f];
    bq.x = lne[kh + 4][f]; bq.y = lne[kh + 5][f];
    bq.z = lne[kh + 6][f]; bq.w = lne[kh + 7][f];
    *reinterpret_cast<float4*>(dst) = a;
    *reinterpret_cast<float4*>(dst + 4) = bq;
  }
}

// =============== K5: GRU-v3 — wave-autonomous staging, ONE barrier ===============
__global__ __launch_bounds__(256) void k5_gru(
    const float* __restrict__ Wu, const float* __restrict__ Uu, const float* __restrict__ bu,
    const float* __restrict__ Wr, const float* __restrict__ Ur, const float* __restrict__ br,
    const float* __restrict__ Wh, const float* __restrict__ Uh, const float* __restrict__ bh,
    const float* __restrict__ ne0T, const float* __restrict__ t0v,
    const float* __restrict__ P, float* __restrict__ Dw) {
  const int b = blockIdx.x, c = blockIdx.y;  // c 0..15
  const int t = threadIdx.x;
  const int w = t >> 6, l = t & 63;
  const int tx = l & 7, ry = l >> 3;
  __shared__ float WA[4][16][40], UA[4][16][40];
  __shared__ float WB[4][16][40], UB[4][16][40];
  __shared__ float Xl[4][16][8], Yl[4][16][8];
  __shared__ float gr[128][9];
  const int row0 = w * 32;
  const int col = c * 8 + tx;
  const float t0c = t0v[b * 64 + (c & 7) * 8 + tx];
  const float* neT = ne0T + (size_t)b * D_ * 64;
  const float* Pb = P + (size_t)b * D_ * D_;
  const int sr = l >> 1, h = l & 1;
  const int e0 = l * 2;
  const int xff = e0 >> 3, xkk = e0 & 7;

  float aU[4] = {}, aR[4] = {};
  for (int f0 = 0; f0 < D_; f0 += 16) {
    {
      const size_t rb = (size_t)(row0 + sr) * D_ + f0 + h * 8;
      const float4 wu0 = *reinterpret_cast<const float4*>(Wu + rb);
      const float4 wu1 = *reinterpret_cast<const float4*>(Wu + rb + 4);
      const float4 uu0 = *reinterpret_cast<const float4*>(Uu + rb);
      const float4 uu1 = *reinterpret_cast<const float4*>(Uu + rb + 4);
      const float4 wr0 = *reinterpret_cast<const float4*>(Wr + rb);
      const float4 wr1 = *reinterpret_cast<const float4*>(Wr + rb + 4);
      const float4 ur0 = *reinterpret_cast<const float4*>(Ur + rb);
      const float4 ur1 = *reinterpret_cast<const float4*>(Ur + rb + 4);
      const float wuv[8] = {wu0.x, wu0.y, wu0.z, wu0.w, wu1.x, wu1.y, wu1.z, wu1.w};
      const float uuv[8] = {uu0.x, uu0.y, uu0.z, uu0.w, uu1.x, uu1.y, uu1.z, uu1.w};
      const float wrv[8] = {wr0.x, wr0.y, wr0.z, wr0.w, wr1.x, wr1.y, wr1.z, wr1.w};
      const float urv[8] = {ur0.x, ur0.y, ur0.z, ur0.w, ur1.x, ur1.y, ur1.z, ur1.w};
      #pragma unroll
      for (int j = 0; j < 8; ++j) {
        WA[w][h * 8 + j][sr] = wuv[j];
        UA[w][h * 8 + j][sr] = uuv[j];
        WB[w][h * 8 + j][sr] = wrv[j];
        UB[w][h * 8 + j][sr] = urv[j];
      }
      #pragma unroll
      for (int e = 0; e < 2; ++e) {
        const int ff = xff, kk = xkk + e;
        Xl[w][ff][kk] = neT[(f0 + ff) * 64 + (c & 7) * 8 + kk];
        Yl[w][ff][kk] = Pb[(size_t)(f0 + ff) * D_ + c * 8 + kk];
      }
    }
    __builtin_amdgcn_wave_barrier();
    #pragma unroll
    for (int ff = 0; ff < 16; ++ff) {
      const float xv = Xl[w][ff][tx] * t0c;
      const float yv = Yl[w][ff][tx];
      const float4 wa = *reinterpret_cast<const float4*>(&WA[w][ff][ry * 4]);
      const float4 ua = *reinterpret_cast<const float4*>(&UA[w][ff][ry * 4]);
      const float4 wb = *reinterpret_cast<const float4*>(&WB[w][ff][ry * 4]);
      const float4 ub = *reinterpret_cast<const float4*>(&UB[w][ff][ry * 4]);
      aU[0] += wa.x * xv + ua.x * yv;
      aU[1] += wa.y * xv + ua.y * yv;
      aU[2] += wa.z * xv + ua.z * yv;
      aU[3] += wa.w * xv + ua.w * yv;
      aR[0] += wb.x * xv + ub.x * yv;
      aR[1] += wb.y * xv + ub.y * yv;
      aR[2] += wb.z * xv + ub.z * yv;
      aR[3] += wb.w * xv + ub.w * yv;
    }
    __builtin_amdgcn_wave_barrier();
  }
  float uval[4];
  #pragma unroll
  for (int r = 0; r < 4; ++r) {
    const int i = row0 + ry * 4 + r;
    uval[r] = 1.f / (1.f + expf(-(aU[r] + bu[i * D_ + col])));
    gr[i][tx] = 1.f / (1.f + expf(-(aR[r] + br[i * D_ + col])));
  }
  __syncthreads();  // the ONE block barrier

  float aH[4] = {};
  for (int f0 = 0; f0 < D_; f0 += 16) {
    {
      const size_t rb = (size_t)(row0 + sr) * D_ + f0 + h * 8;
      const float4 wh0 = *reinterpret_cast<const float4*>(Wh + rb);
      const float4 wh1 = *reinterpret_cast<const float4*>(Wh + rb + 4);
      const float4 uh0 = *reinterpret_cast<const float4*>(Uh + rb);
      const float4 uh1 = *reinterpret_cast<const float4*>(Uh + rb + 4);
      const float whv[8] = {wh0.x, wh0.y, wh0.z, wh0.w, wh1.x, wh1.y, wh1.z, wh1.w};
      const float uhv[8] = {uh0.x, uh0.y, uh0.z, uh0.w, uh1.x, uh1.y, uh1.z, uh1.w};
      #pragma unroll
      for (int j = 0; j < 8; ++j) {
        WA[w][h * 8 + j][sr] = whv[j];
        UA[w][h * 8 + j][sr] = uhv[j];
      }
      #pragma unroll
      for (int e = 0; e < 2; ++e) {
        const int ff = xff, kk = xkk + e;
        Xl[w][ff][kk] = neT[(f0 + ff) * 64 + (c & 7) * 8 + kk];
        Yl[w][ff][kk] = gr[f0 + ff][kk] * Pb[(size_t)(f0 + ff) * D_ + c * 8 + kk];
      }
    }
    __builtin_amdgcn_wave_barrier();
    #pragma unroll
    for (int ff = 0; ff < 16; ++ff) {
      const float xv = Xl[w][ff][tx] * t0c;
      const float yv = Yl[w][ff][tx];
      const float4 wa = *reinterpret_cast<const float4*>(&WA[w][ff][ry * 4]);
      const float4 ua = *reinterpret_cast<const float4*>(&UA[w][ff][ry * 4]);
      aH[0] += wa.x * xv + ua.x * yv;
      aH[1] += wa.y * xv + ua.y * yv;
      aH[2] += wa.z * xv + ua.z * yv;
      aH[3] += wa.w * xv + ua.w * yv;
    }
    __builtin_amdgcn_wave_barrier();
  }
  #pragma unroll
  for (int r = 0; r < 4; ++r) {
    const int i = row0 + ry * 4 + r;
    const float hh = tanhf(aH[r] + bh[i * D_ + col]);
    const float pp = Pb[(size_t)i * D_ + col];
    Dw[((size_t)b * D_ + i) * D_ + col] = (1.f - uval[r]) * pp + uval[r] * hh;
  }
}

// =============== K6: GCN1-v2 — 3 barriers ===============
__global__ __launch_bounds__(256) void k6_gcn1(
    const float* __restrict__ ne0T, const float* __restrict__ Dw,
    const float* __restrict__ A0r, float* __restrict__ h1ws) {
  const int b = blockIdx.x, c = blockIdx.y;
  const int t = threadIdx.x;
  const int w = t >> 6, l = t & 63;
  const int tx = t & 15, ty = t >> 4;
  const int cg = l & 3, rg = l >> 2;
  const int row = w * 16 + rg;
  __shared__ float As[64][68];
  __shared__ float di[64];
  __shared__ float Ts[64][24];
  __shared__ float At[4][16][24], Bt[4][16][24];
  const float* Ab = A0r + (size_t)b * 4096;
  const float* neT = ne0T + (size_t)b * D_ * 64;
  const float* Db = Dw + (size_t)b * D_ * D_;
  #pragma unroll
  for (int ph = 0; ph < 4; ++ph) {
    const int i = ph * 16 + ty;
    *reinterpret_cast<float4*>(&As[i][tx * 4]) =
        *reinterpret_cast<const float4*>(Ab + i * 64 + tx * 4);
  }
  __syncthreads();
  if (t < 64) {
    float s = 0.f;
    #pragma unroll
    for (int i = 0; i < 64; ++i) s += As[i][t];
    di[t] = 1.0f / sqrtf(2.0f * s);
  }
  __syncthreads();
  #pragma unroll
  for (int ph = 0; ph < 4; ++ph) {
    const int i = ph * 16 + ty;
    const float sI = 2.0f * di[i];
    float4 v = *reinterpret_cast<float4*>(&As[i][tx * 4]);
    v.x *= sI * di[tx * 4];
    v.y *= sI * di[tx * 4 + 1];
    v.z *= sI * di[tx * 4 + 2];
    v.w *= sI * di[tx * 4 + 3];
    *reinterpret_cast<float4*>(&As[i][tx * 4]) = v;
  }
  const int sff = l >> 2, sq = (l & 3) * 4;
  float acc[4] = {};
  for (int f0 = 0; f0 < D_; f0 += 16) {
    {
      const float4 av = *reinterpret_cast<const float4*>(neT + (f0 + sff) * 64 + w * 16 + sq);
      *reinterpret_cast<float4*>(&At[w][sff][sq]) = av;
      const float4 bv = *reinterpret_cast<const float4*>(Db + (size_t)(f0 + sff) * D_ + c * 16 + sq);
      *reinterpret_cast<float4*>(&Bt[w][sff][sq]) = bv;
    }
    __builtin_amdgcn_wave_barrier();
    #pragma unroll
    for (int ff = 0; ff < 16; ++ff) {
      const float a = At[w][ff][rg];
      const float4 b4 = *reinterpret_cast<const float4*>(&Bt[w][ff][cg * 4]);
      acc[0] += a * b4.x;
      acc[1] += a * b4.y;
      acc[2] += a * b4.z;
      acc[3] += a * b4.w;
    }
    __builtin_amdgcn_wave_barrier();
  }
  {
    float4 o = {acc[0], acc[1], acc[2], acc[3]};
    *reinterpret_cast<float4*>(&Ts[row][cg * 4]) = o;
  }
  __syncthreads();
  float a2[4] = {};
  for (int ff = 0; ff < 64; ++ff) {
    const float a = As[row][ff];
    const float4 b4 = *reinterpret_cast<const float4*>(&Ts[ff][cg * 4]);
    a2[0] += a * b4.x;
    a2[1] += a * b4.y;
    a2[2] += a * b4.z;
    a2[3] += a * b4.w;
  }
  {
    float4 o = {fmaxf(a2[0], 0.f), fmaxf(a2[1], 0.f),
                fmaxf(a2[2], 0.f), fmaxf(a2[3], 0.f)};
    *reinterpret_cast<float4*>(h1ws + ((size_t)b * 64 + row) * D_ + c * 16 + cg * 4) = o;
  }
}

// =============== K7: GCN2-v2 — 3 barriers ===============
__global__ __launch_bounds__(256) void k7_gcn2(
    const float* __restrict__ h1ws, const float* __restrict__ sw,
    const float* __restrict__ A0r, float* __restrict__ out) {
  const int b = blockIdx.x, c = blockIdx.y;
  const int t = threadIdx.x;
  const int w = t >> 6, l = t & 63;
  const int tx = t & 15, ty = t >> 4;
  const int cg = l & 3, rg = l >> 2;
  const int row = w * 16 + rg;
  __shared__ float As[64][68];
  __shared__ float di[64];
  __shared__ float Ts[64][24];
  __shared__ float At[4][16][24], Bt[4][16][24];
  const float* Ab = A0r + (size_t)b * 4096;
  const float* h1b = h1ws + (size_t)b * 64 * D_;
  #pragma unroll
  for (int ph = 0; ph < 4; ++ph) {
    const int i = ph * 16 + ty;
    *reinterpret_cast<float4*>(&As[i][tx * 4]) =
        *reinterpret_cast<const float4*>(Ab + i * 64 + tx * 4);
  }
  __syncthreads();
  if (t < 64) {
    float s = 0.f;
    #pragma unroll
    for (int i = 0; i < 64; ++i) s += As[i][t];
    di[t] = 1.0f / sqrtf(2.0f * s);
  }
  __syncthreads();
  #pragma unroll
  for (int ph = 0; ph < 4; ++ph) {
    const int i = ph * 16 + ty;
    const float sI = 2.0f * di[i];
    float4 v = *reinterpret_cast<float4*>(&As[i][tx * 4]);
    v.x *= sI * di[tx * 4];
    v.y *= sI * di[tx * 4 + 1];
    v.z *= sI * di[tx * 4 + 2];
    v.w *= sI * di[tx * 4 + 3];
    *reinterpret_cast<float4*>(&As[i][tx * 4]) = v;
  }
  const int sr16 = l & 15, sh4 = l >> 4;
  const int sff = l >> 2, sq = (l & 3) * 4;
  float acc[4] = {};
  for (int f0 = 0; f0 < D_; f0 += 16) {
    {
      const float4 hv = *reinterpret_cast<const float4*>(
          h1b + (size_t)(w * 16 + sr16) * D_ + f0 + sh4 * 4);
      At[w][sh4 * 4 + 0][sr16] = hv.x;
      At[w][sh4 * 4 + 1][sr16] = hv.y;
      At[w][sh4 * 4 + 2][sr16] = hv.z;
      At[w][sh4 * 4 + 3][sr16] = hv.w;
      const float4 bv = *reinterpret_cast<const float4*>(sw + (size_t)(f0 + sff) * D_ + c * 16 + sq);
      *reinterpret_cast<float4*>(&Bt[w][sff][sq]) = bv;
    }
    __builtin_amdgcn_wave_barrier();
    #pragma unroll
    for (int ff = 0; ff < 16; ++ff) {
      const float a = At[w][ff][rg];
      const float4 b4 = *reinterpret_cast<const float4*>(&Bt[w][ff][cg * 4]);
      acc[0] += a * b4.x;
      acc[1] += a * b4.y;
      acc[2] += a * b4.z;
      acc[3] += a * b4.w;
    }
    __builtin_amdgcn_wave_barrier();
  }
  {
    float4 o = {acc[0], acc[1], acc[2], acc[3]};
    *reinterpret_cast<float4*>(&Ts[row][cg * 4]) = o;
  }
  __syncthreads();
  float a2[4] = {};
  for (int ff = 0; ff < 64; ++ff) {
    const float a = As[row][ff];
    const float4 b4 = *reinterpret_cast<const float4*>(&Ts[ff][cg * 4]);
    a2[0] += a * b4.x;
    a2[1] += a * b4.y;
    a2[2] += a * b4.z;
    a2[3] += a * b4.w;
  }
  {
    const int k = c * 16 + cg * 4;
    const float4 h1v = *reinterpret_cast<const float4*>(h1b + (size_t)row * D_ + k);
    float4 o;
    o.x = 0.5f * (h1v.x + fmaxf(a2[0], 0.f));
    o.y = 0.5f * (h1v.y + fmaxf(a2[1], 0.f));
    o.z = 0.5f * (h1v.z + fmaxf(a2[2], 0.f));
    o.w = 0.5f * (h1v.w + fmaxf(a2[3], 0.f));
    *reinterpret_cast<float4*>(out + ((size_t)b * D_ + row) * D_ + k) = o;
    *reinterpret_cast<float4*>(out + ((size_t)b * D_ + row + 64) * D_ + k) = o;
  }
}

}  // namespace

extern "C" void kernel_launch(void* const* d_in, const int* in_sizes, int n_in,
                              void* d_out, int out_size, void* d_ws, size_t ws_size,
                              hipStream_t stream) {
  (void)in_sizes; (void)n_in; (void)out_size; (void)ws_size;
  const float* Ahat = (const float*)d_in[0];
  const float* node = (const float*)d_in[1];
  const float* ht   = (const float*)d_in[2];
  const float* prevD= (const float*)d_in[3];
  const float* mw   = (const float*)d_in[4];
  const float* mb   = (const float*)d_in[5];
  const float* Wu   = (const float*)d_in[6];
  const float* Uu   = (const float*)d_in[7];
  const float* bu   = (const float*)d_in[8];
  const float* Wr   = (const float*)d_in[9];
  const float* Ur   = (const float*)d_in[10];
  const float* br   = (const float*)d_in[11];
  const float* Wh   = (const float*)d_in[12];
  const float* Uh   = (const float*)d_in[13];
  const float* bh   = (const float*)d_in[14];
  const float* sw   = (const float*)d_in[15];

  float* out = (float*)d_out;
  float* outPolicy  = out + (size_t)B_ * D_ * D_;
  float* outScorer  = outPolicy + B_;
  float* outEntropy = outScorer + (size_t)B_ * D_;

  float* ws = (float*)d_ws;
  float* scorer = ws + OFF_SCORER;
  float* invn   = ws + OFF_INVN;
  float* cand_v = ws + OFF_CANDV;
  int*   cand_i = (int*)(ws + OFF_CANDI);
  float* stats  = ws + OFF_STATS;
  int*   tki    = (int*)(ws + OFF_TKI);
  float* t0v    = ws + OFF_T0;
  float* ne0T   = ws + OFF_NE0T;
  float* A0r    = ws + OFF_A0R;
  float* Dw     = ws + OFF_DW;
  float* h1ws   = ws + OFF_H1;

  k1_scorer<<<B_, 1024, 0, stream>>>(ht, mw, mb, scorer, invn, outScorer);
  k2_scores<<<dim3(B_, 8), 512, 0, stream>>>(node, scorer, invn, cand_v, cand_i, stats);
  k3_merge<<<B_, 1024, 0, stream>>>(cand_v, cand_i, stats, node, Ahat, tki, t0v,
                                    outPolicy, outEntropy, ne0T, A0r);
  k5_gru<<<dim3(B_, 16), 256, 0, stream>>>(Wu, Uu, bu, Wr, Ur, br, Wh, Uh, bh,
                                           ne0T, t0v, prevD, Dw);
  k6_gcn1<<<dim3(B_, 8), 256, 0, stream>>>(ne0T, Dw, A0r, h1ws);
  k7_gcn2<<<dim3(B_, 8), 256, 0, stream>>>(h1ws, sw, A0r, out);
}